// Round 5
// baseline (1310.299 us; speedup 1.0000x reference)
//
#include <hip/hip_runtime.h>

// KruskalLinearLayer: y[n,abc] = sum_r g0[a,r]g1[b,r]g2[c,r] * s[n,r] + bias
//   s[n,r] = sum_{d,e,f} g3[d,r]g4[e,r]g5[f,r] * x[n,def]
//   g_m = f_m @ c_m   (16x8 @ 8x16 = 16x16)
//
// R1-R4 lesson: a single fused kernel ALWAYS spilled (470-860 MB scratch
// writes) because the scheduler merges phase-1 (xv[16]=64 regs) and
// phase-2 (coef[16]=64 regs) live ranges no matter how the source is
// scoped. R5: hard wall = two kernels through d_ws (S = 4096x16 fp32,
// 256 KB, L2-hot). Each kernel's peak live ~90 regs, fits 128-VGPR cap.

typedef float f32x4 __attribute__((ext_vector_type(4)));

#define WAVES_PER_BLOCK 4

// ---------------- Kernel A: S[n,r] = sum_def g3 g4 g5 x ----------------
__global__ __launch_bounds__(256, 2)
void kruskal_phase1(const float* __restrict__ x,
                    const float* __restrict__ c3, const float* __restrict__ c4,
                    const float* __restrict__ c5,
                    const float* __restrict__ f3, const float* __restrict__ f4,
                    const float* __restrict__ f5,
                    float* __restrict__ S,
                    int N)
{
    // gt[m][r][idx] = g_m[idx][r]
    __shared__ __align__(16) float gt3[256], gt4[256], gt5[256];
    const int tid = threadIdx.x;
    {
        const int r = tid >> 4, a = tid & 15;
        float a3 = 0.f, a4 = 0.f, a5 = 0.f;
#pragma unroll
        for (int k = 0; k < 8; ++k) {
            a3 += f3[a * 8 + k] * c3[k * 16 + r];
            a4 += f4[a * 8 + k] * c4[k * 16 + r];
            a5 += f5[a * 8 + k] * c5[k * 16 + r];
        }
        gt3[r * 16 + a] = a3;
        gt4[r * 16 + a] = a4;
        gt5[r * 16 + a] = a5;
    }
    __syncthreads();

    const int lane   = tid & 63;
    const int waveId = tid >> 6;
    const int eb     = lane >> 2;        // e
    const int fcb    = (lane & 3) * 4;   // f base
    const int totalWaves = gridDim.x * WAVES_PER_BLOCK;

    for (int n = blockIdx.x * WAVES_PER_BLOCK + waveId; n < N; n += totalWaves) {
        const float* xn = x + (size_t)n * 4096;

        // all 16 x-chunks up front: 64 VGPRs, max MLP (fits the 128 cap)
        f32x4 xv[16];
#pragma unroll
        for (int d = 0; d < 16; ++d)
            xv[d] = __builtin_nontemporal_load(
                (const f32x4*)(xn + d * 256 + lane * 4));

        float s[16];
#pragma unroll
        for (int r = 0; r < 16; ++r) {
            const float* g3r = &gt3[r * 16];
            f32x4 t = {0.f, 0.f, 0.f, 0.f};
#pragma unroll
            for (int d = 0; d < 16; ++d)
                t += g3r[d] * xv[d];
            const f32x4 g5v = *(const f32x4*)(&gt5[r * 16 + fcb]);
            const float p = t.x * g5v.x + t.y * g5v.y + t.z * g5v.z + t.w * g5v.w;
            s[r] = p * gt4[r * 16 + eb];
        }

        // wave-wide sum of each s[r]
#pragma unroll
        for (int r = 0; r < 16; ++r) {
            float v = s[r];
            v += __shfl_xor(v, 1, 64);
            v += __shfl_xor(v, 2, 64);
            v += __shfl_xor(v, 4, 64);
            v += __shfl_xor(v, 8, 64);
            v += __shfl_xor(v, 16, 64);
            v += __shfl_xor(v, 32, 64);
            s[r] = v;
        }

        // lane r (r<16) stores S[n*16+r]
        float outv = s[0];
#pragma unroll
        for (int r = 1; r < 16; ++r)
            if (lane == r) outv = s[r];
        if (lane < 16)
            S[(size_t)n * 16 + lane] = outv;
    }
}

// ---------------- Kernel B: y[n,abc] = sum_r g0 g1 g2 S + bias ----------------
__global__ __launch_bounds__(256, 2)
void kruskal_phase2(const float* __restrict__ S,
                    const float* __restrict__ c0, const float* __restrict__ c1,
                    const float* __restrict__ c2,
                    const float* __restrict__ f0, const float* __restrict__ f1,
                    const float* __restrict__ f2,
                    const float* __restrict__ bias,
                    float* __restrict__ out,
                    int N)
{
    __shared__ __align__(16) float g0n[256];   // g0 in [a][r] layout
    __shared__ __align__(16) float gt1[256];   // [r][b]
    __shared__ __align__(16) float gt2[256];   // [r][c]
    __shared__ __align__(16) float sb[4096];   // bias

    const int tid = threadIdx.x;
    {
        const int r = tid >> 4, a = tid & 15;
        float a0 = 0.f, a1 = 0.f, a2 = 0.f;
#pragma unroll
        for (int k = 0; k < 8; ++k) {
            a0 += f0[a * 8 + k] * c0[k * 16 + r];
            a1 += f1[a * 8 + k] * c1[k * 16 + r];
            a2 += f2[a * 8 + k] * c2[k * 16 + r];
        }
        g0n[a * 16 + r] = a0;
        gt1[r * 16 + a] = a1;
        gt2[r * 16 + a] = a2;
    }
#pragma unroll
    for (int t = 0; t < 16; ++t)
        sb[t * 256 + tid] = bias[t * 256 + tid];
    __syncthreads();

    const int lane   = tid & 63;
    const int waveId = tid >> 6;
    const int eb     = lane >> 2;        // b
    const int fcb    = (lane & 3) * 4;   // c base
    const int totalWaves = gridDim.x * WAVES_PER_BLOCK;

    for (int n = blockIdx.x * WAVES_PER_BLOCK + waveId; n < N; n += totalWaves) {
        // S row: 64 B, all lanes same address -> broadcast, L2-hot
        const f32x4* Sr = (const f32x4*)(S + (size_t)n * 16);
        const f32x4 sv0 = Sr[0], sv1 = Sr[1], sv2 = Sr[2], sv3 = Sr[3];
        float s[16] = {sv0.x, sv0.y, sv0.z, sv0.w,  sv1.x, sv1.y, sv1.z, sv1.w,
                       sv2.x, sv2.y, sv2.z, sv2.w,  sv3.x, sv3.y, sv3.z, sv3.w};

        f32x4 coef[16];
#pragma unroll
        for (int r = 0; r < 16; ++r) {
            const f32x4 g2v = *(const f32x4*)(&gt2[r * 16 + fcb]);
            coef[r] = g2v * (gt1[r * 16 + eb] * s[r]);
        }

        float* yn = out + (size_t)n * 4096;
#pragma unroll
        for (int a = 0; a < 16; ++a) {
            f32x4 acc = *(const f32x4*)(&sb[a * 256 + lane * 4]);  // init = bias
            const f32x4* g0a = (const f32x4*)(&g0n[a * 16]);
#pragma unroll
            for (int rq = 0; rq < 4; ++rq) {
                const f32x4 g = g0a[rq];   // lane-uniform LDS broadcast
                acc += g.x * coef[rq * 4 + 0];
                acc += g.y * coef[rq * 4 + 1];
                acc += g.z * coef[rq * 4 + 2];
                acc += g.w * coef[rq * 4 + 3];
            }
            __builtin_nontemporal_store(acc, (f32x4*)(yn + a * 256 + lane * 4));
        }
    }
}

extern "C" void kernel_launch(void* const* d_in, const int* in_sizes, int n_in,
                              void* d_out, int out_size, void* d_ws, size_t ws_size,
                              hipStream_t stream) {
    const float* x  = (const float*)d_in[0];
    const float* c0 = (const float*)d_in[1];
    const float* c1 = (const float*)d_in[2];
    const float* c2 = (const float*)d_in[3];
    const float* c3 = (const float*)d_in[4];
    const float* c4 = (const float*)d_in[5];
    const float* c5 = (const float*)d_in[6];
    const float* f0 = (const float*)d_in[7];
    const float* f1 = (const float*)d_in[8];
    const float* f2 = (const float*)d_in[9];
    const float* f3 = (const float*)d_in[10];
    const float* f4 = (const float*)d_in[11];
    const float* f5 = (const float*)d_in[12];
    const float* bias = (const float*)d_in[13];
    float* out = (float*)d_out;
    float* S   = (float*)d_ws;          // N x 16 fp32 = 256 KB

    const int N = in_sizes[0] / 4096;
    const int grid = (N + WAVES_PER_BLOCK - 1) / WAVES_PER_BLOCK;

    kruskal_phase1<<<dim3(grid), dim3(256), 0, stream>>>(
        x, c3, c4, c5, f3, f4, f5, S, N);
    kruskal_phase2<<<dim3(grid), dim3(256), 0, stream>>>(
        S, c0, c1, c2, f0, f1, f2, bias, out, N);
}

// Round 6
// 151.793 us; speedup vs baseline: 8.6321x; 8.6321x over previous
//
#include <hip/hip_runtime.h>

// KruskalLinearLayer: y[n,abc] = sum_r g0[a,r]g1[b,r]g2[c,r] * s[n,r] + bias
//   s[n,r] = sum_{d,e,f} g3[d,r]g4[e,r]g5[f,r] * x[n,def]
//   g_m = f_m @ c_m   (16x8 @ 8x16 = 16x16)
//
// R1-R5 lesson: every structure with a PER-ROW 64-VGPR array (xv[16] or
// coef[16]) spilled to scratch (up to 2.3 GB of traffic) regardless of
// launch_bounds / scoping — the scheduler hoists loads across unrolled
// loops and busts the cap. R6: the big arrays are now LOOP-INVARIANT
// per-wave weights (w1[r] / w[r]) loaded ONCE; the per-row live set is
// ~25 regs. Two kernels through d_ws (S = N x 16 fp32, 256 KB, L2-hot)
// keep the phases' register pressure independent.

typedef float f32x4 __attribute__((ext_vector_type(4)));

#define WPB 4   // waves per block

// ---------------- Kernel A: S[n,r] = sum_def g3 g4 g5 x ----------------
// wave per row; lane owns cols ef = lane*4..+4 of each d-slab.
// w1[r] = g4[e,r] * g5[f.. ,r]  (lane-fixed, row-invariant -> 64 regs, free)
__global__ __launch_bounds__(256, 2)
void kruskal_phase1(const float* __restrict__ x,
                    const float* __restrict__ c3, const float* __restrict__ c4,
                    const float* __restrict__ c5,
                    const float* __restrict__ f3, const float* __restrict__ f4,
                    const float* __restrict__ f5,
                    float* __restrict__ S, int N)
{
    __shared__ __align__(16) float g3t[256];  // [d][r]
    __shared__ __align__(16) float g4t[256];  // [r][e]
    __shared__ __align__(16) float g5t[256];  // [r][f]
    const int tid = threadIdx.x;
    {
        const int i = tid >> 4, r = tid & 15;
        float a3 = 0.f, a4 = 0.f, a5 = 0.f;
#pragma unroll
        for (int k = 0; k < 8; ++k) {
            a3 += f3[i * 8 + k] * c3[k * 16 + r];
            a4 += f4[i * 8 + k] * c4[k * 16 + r];
            a5 += f5[i * 8 + k] * c5[k * 16 + r];
        }
        g3t[i * 16 + r] = a3;   // [d][r]
        g4t[r * 16 + i] = a4;   // [r][e]
        g5t[r * 16 + i] = a5;   // [r][f]
    }
    __syncthreads();

    const int lane = tid & 63, waveId = tid >> 6;
    const int eb  = lane >> 2;         // e
    const int fcb = (lane & 3) * 4;    // f base

    // loop-invariant lane weights (the ONLY big register array)
    f32x4 w1[16];
#pragma unroll
    for (int r = 0; r < 16; ++r)
        w1[r] = (*(const f32x4*)&g5t[r * 16 + fcb]) * g4t[r * 16 + eb];

    const int wgl   = blockIdx.x * WPB + waveId;
    const int total = gridDim.x * WPB;
    for (int n = wgl; n < N; n += total) {
        const float* xn = x + (size_t)n * 4096;
        float s[16];
#pragma unroll
        for (int r = 0; r < 16; ++r) s[r] = 0.f;

        // stream x one float4 at a time; unroll 2 ONLY (forbid hoisting
        // all 16 loads = the R2/R4 spill trigger)
#pragma unroll 2
        for (int d = 0; d < 16; ++d) {
            const f32x4 xd = __builtin_nontemporal_load(
                (const f32x4*)(xn + d * 256 + lane * 4));
#pragma unroll
            for (int rq = 0; rq < 4; ++rq) {
                const f32x4 g3q = *(const f32x4*)&g3t[d * 16 + rq * 4]; // uniform
#pragma unroll
                for (int rr = 0; rr < 4; ++rr) {
                    const int r = rq * 4 + rr;
                    const float p = w1[r].x * xd.x + w1[r].y * xd.y
                                  + w1[r].z * xd.z + w1[r].w * xd.w;
                    s[r] += g3q[rr] * p;
                }
            }
        }

        // wave-wide sum of each s[r]
#pragma unroll
        for (int r = 0; r < 16; ++r) {
            float v = s[r];
            v += __shfl_xor(v, 1, 64);
            v += __shfl_xor(v, 2, 64);
            v += __shfl_xor(v, 4, 64);
            v += __shfl_xor(v, 8, 64);
            v += __shfl_xor(v, 16, 64);
            v += __shfl_xor(v, 32, 64);
            s[r] = v;
        }
        float outv = s[0];
#pragma unroll
        for (int r = 1; r < 16; ++r)
            if (lane == r) outv = s[r];
        if (lane < 16)
            S[(size_t)n * 16 + lane] = outv;
    }
}

// ---------------- Kernel B: y[n,abc] = sum_r g0 g1 g2 S + bias ----------------
// wave pinned to output chunk a (256 cols); w[r] & bias loaded once.
__global__ __launch_bounds__(256, 2)
void kruskal_phase2(const float* __restrict__ S,
                    const float* __restrict__ c0, const float* __restrict__ c1,
                    const float* __restrict__ c2,
                    const float* __restrict__ f0, const float* __restrict__ f1,
                    const float* __restrict__ f2,
                    const float* __restrict__ bias,
                    float* __restrict__ out, int N)
{
    __shared__ __align__(16) float g0t[256];  // [r][a]
    __shared__ __align__(16) float g1t[256];  // [r][b]
    __shared__ __align__(16) float g2t[256];  // [r][c]
    const int tid = threadIdx.x;
    {
        const int i = tid >> 4, r = tid & 15;
        float a0 = 0.f, a1 = 0.f, a2 = 0.f;
#pragma unroll
        for (int k = 0; k < 8; ++k) {
            a0 += f0[i * 8 + k] * c0[k * 16 + r];
            a1 += f1[i * 8 + k] * c1[k * 16 + r];
            a2 += f2[i * 8 + k] * c2[k * 16 + r];
        }
        g0t[r * 16 + i] = a0;
        g1t[r * 16 + i] = a1;
        g2t[r * 16 + i] = a2;
    }
    __syncthreads();

    const int lane = tid & 63, waveId = tid >> 6;
    const int eb  = lane >> 2;         // b
    const int fcb = (lane & 3) * 4;    // c base

    const int wgl    = blockIdx.x * WPB + waveId;   // 0 .. totalWaves-1
    const int chunk  = wgl & 15;                    // a  (wave-fixed)
    const int slot   = wgl >> 4;
    const int stride = (gridDim.x * WPB) >> 4;

    // kernel-invariant lane weights + bias chunk
    f32x4 w[16];
#pragma unroll
    for (int r = 0; r < 16; ++r)
        w[r] = (*(const f32x4*)&g2t[r * 16 + fcb])
             * (g0t[r * 16 + chunk] * g1t[r * 16 + eb]);
    const f32x4 bv = *(const f32x4*)(bias + chunk * 256 + lane * 4);

#pragma unroll 1
    for (int n = slot; n < N; n += stride) {
        const f32x4* Sr = (const f32x4*)(S + (size_t)n * 16);  // uniform, L2-hot
        const f32x4 s0 = Sr[0], s1 = Sr[1], s2 = Sr[2], s3 = Sr[3];
        f32x4 acc = bv;
        acc += s0.x * w[0];  acc += s0.y * w[1];
        acc += s0.z * w[2];  acc += s0.w * w[3];
        acc += s1.x * w[4];  acc += s1.y * w[5];
        acc += s1.z * w[6];  acc += s1.w * w[7];
        acc += s2.x * w[8];  acc += s2.y * w[9];
        acc += s2.z * w[10]; acc += s2.w * w[11];
        acc += s3.x * w[12]; acc += s3.y * w[13];
        acc += s3.z * w[14]; acc += s3.w * w[15];
        __builtin_nontemporal_store(
            acc, (f32x4*)(out + (size_t)n * 4096 + chunk * 256 + lane * 4));
    }
}

extern "C" void kernel_launch(void* const* d_in, const int* in_sizes, int n_in,
                              void* d_out, int out_size, void* d_ws, size_t ws_size,
                              hipStream_t stream) {
    const float* x  = (const float*)d_in[0];
    const float* c0 = (const float*)d_in[1];
    const float* c1 = (const float*)d_in[2];
    const float* c2 = (const float*)d_in[3];
    const float* c3 = (const float*)d_in[4];
    const float* c4 = (const float*)d_in[5];
    const float* c5 = (const float*)d_in[6];
    const float* f0 = (const float*)d_in[7];
    const float* f1 = (const float*)d_in[8];
    const float* f2 = (const float*)d_in[9];
    const float* f3 = (const float*)d_in[10];
    const float* f4 = (const float*)d_in[11];
    const float* f5 = (const float*)d_in[12];
    const float* bias = (const float*)d_in[13];
    float* out = (float*)d_out;
    float* S   = (float*)d_ws;          // N x 16 fp32 = 256 KB

    const int N = in_sizes[0] / 4096;

    kruskal_phase1<<<dim3(1024), dim3(256), 0, stream>>>(
        x, c3, c4, c5, f3, f4, f5, S, N);
    kruskal_phase2<<<dim3(1024), dim3(256), 0, stream>>>(
        S, c0, c1, c2, f0, f1, f2, bias, out, N);
}